// Round 8
// baseline (2641.964 us; speedup 1.0000x reference)
//
#include <hip/hip_runtime.h>

// NUMERIC CONTRACT: one __fmaf_rn per support tap, ky-outer/kx-inner order,
// per-candidate sequential chains, acc starts at +0.0f, final u+best via
// __fadd_rn. __fmaf_rn lowers to llvm.fma -> v_fma_f32 / v_pk_fma_f32
// (identical per-lane values), so the FP chain is deterministic regardless
// of CSE/SLP/scheduling. This reproduces the backend-fused chain of the
// R4 kernel that PASSED (absmax 7.8e-3) while allowing fast data movement.

// Problem constants
#define H 2048
#define W 2048
#define C 3
#define RAD 5
#define P (H + 2*RAD)           // 2058 padded state dimension
#define RS 2064                 // row stride (16-float aligned)
#define PLANE ((size_t)P * RS)  // elements per channel plane
#define NITER 10

// Step-kernel tile: 128 x 8 outputs per block, threads (32,8), 4 px/thread
#define BX 128
#define BY 8
#define EX (BX + 2*RAD)         // 138
#define EY (BY + 2*RAD)         // 18
#define LSX 144                 // LDS row stride (float4-aligned)

// ---------------------------------------------------------------------------
// Pad: HWC f32 img -> 3 planar padded f32 planes (edge replication)
// ---------------------------------------------------------------------------
__global__ void pad_kernel(const float* __restrict__ img, float* __restrict__ dst) {
    int idx = blockIdx.x * blockDim.x + threadIdx.x;
    int total = C * P * P;
    if (idx >= total) return;
    int c = idx / (P * P);
    int rem = idx - c * (P * P);
    int y = rem / P;
    int x = rem - y * P;
    int ys = min(max(y - RAD, 0), H - 1);
    int xs = min(max(x - RAD, 0), W - 1);
    dst[c * PLANE + (size_t)y * RS + x] = img[((size_t)ys * W + xs) * C + c];
}

__device__ __forceinline__ float select8(const float* a) {
    float best = a[0], ba = fabsf(a[0]), t;
    t = fabsf(a[1]); if (t < ba) { ba = t; best = a[1]; }
    t = fabsf(a[2]); if (t < ba) { ba = t; best = a[2]; }
    t = fabsf(a[3]); if (t < ba) { ba = t; best = a[3]; }
    t = fabsf(a[4]); if (t < ba) { ba = t; best = a[4]; }
    t = fabsf(a[5]); if (t < ba) { ba = t; best = a[5]; }
    t = fabsf(a[6]); if (t < ba) { ba = t; best = a[6]; }
    t = fabsf(a[7]); if (t < ba) { ba = t; best = a[7]; }
    return best;
}

// ---------------------------------------------------------------------------
// One side-window iteration. FMA-per-tap chains (see contract above);
// 4 px/thread register window loaded via float4 LDS reads.
// ---------------------------------------------------------------------------
__global__ __launch_bounds__(256)
void step_kernel(const float* __restrict__ src, float* __restrict__ dst,
                 const float* __restrict__ kern) {
    __shared__ __align__(16) float sU[EY][LSX];

    // Exact f32 weights: kernel[0]=LL corner, kernel[4]=Lk side.
    const float w36 = kern[0];
    const float c36 = kern[5 * 11 + 5];
    const float w66 = kern[4 * 121];
    const float c66 = kern[4 * 121 + 5 * 11 + 5];

    const int ch = blockIdx.z;
    const float* plane = src + (size_t)ch * PLANE;
    const int x0 = blockIdx.x * BX;
    const int y0 = blockIdx.y * BY;
    const int tid = threadIdx.y * 32 + threadIdx.x;   // blockDim = (32,8)

    // Stage tile + halo; outside [0,P) is zero (conv zero padding)
    for (int i = tid; i < EY * EX; i += 256) {
        int r   = i / EX;
        int col = i - r * EX;
        int gy = y0 - RAD + r;
        int gx = x0 - RAD + col;
        float v = 0.0f;
        if (gy >= 0 && gy < P && gx >= 0 && gx < P)
            v = plane[(size_t)gy * RS + gx];
        sU[r][col] = v;
    }
    __syncthreads();

    const int r   = threadIdx.y;          // output row within tile
    const int X   = threadIdx.x * 4;      // first of 4 output columns
    const int gy  = y0 + r;
    const int gx0 = x0 + X;

    float acc[4][8];
    #pragma unroll
    for (int p = 0; p < 4; ++p)
        #pragma unroll
        for (int i = 0; i < 8; ++i) acc[p][i] = 0.0f;
    float uc[4] = {0.f, 0.f, 0.f, 0.f};

    #pragma unroll
    for (int ky = 0; ky < 11; ++ky) {
        const float4* prow = reinterpret_cast<const float4*>(&sU[r + ky][X]);
        float4 q0 = prow[0], q1 = prow[1], q2 = prow[2], q3 = prow[3];
        float win[14];
        win[0]=q0.x;  win[1]=q0.y;  win[2]=q0.z;  win[3]=q0.w;
        win[4]=q1.x;  win[5]=q1.y;  win[6]=q1.z;  win[7]=q1.w;
        win[8]=q2.x;  win[9]=q2.y;  win[10]=q2.z; win[11]=q2.w;
        win[12]=q3.x; win[13]=q3.y;

        if (ky == 5) { uc[0]=win[5]; uc[1]=win[6]; uc[2]=win[7]; uc[3]=win[8]; }

        #pragma unroll
        for (int kx = 0; kx < 11; ++kx) {
            const bool Lv = (ky <= 5), Rv = (ky >= 5);
            const bool Lh = (kx <= 5), Rh = (kx >= 5);
            const bool ctr = (ky == 5) && (kx == 5);
            const float wc = ctr ? c36 : w36;
            const float ws = ctr ? c66 : w66;
            #pragma unroll
            for (int p = 0; p < 4; ++p) {
                const float uv = win[kx + p];
                if (Lv && Lh) acc[p][0] = __fmaf_rn(wc, uv, acc[p][0]);  // LL
                if (Lv && Rh) acc[p][1] = __fmaf_rn(wc, uv, acc[p][1]);  // LR
                if (Rv && Lh) acc[p][2] = __fmaf_rn(wc, uv, acc[p][2]);  // RL
                if (Rv && Rh) acc[p][3] = __fmaf_rn(wc, uv, acc[p][3]);  // RR
                if (Lv)       acc[p][4] = __fmaf_rn(ws, uv, acc[p][4]);  // Lk
                if (Rv)       acc[p][5] = __fmaf_rn(ws, uv, acc[p][5]);  // Rk
                if (Lh)       acc[p][6] = __fmaf_rn(ws, uv, acc[p][6]);  // kL
                if (Rh)       acc[p][7] = __fmaf_rn(ws, uv, acc[p][7]);  // kR
            }
        }
    }

    if (gy < P) {
        float r0 = __fadd_rn(uc[0], select8(acc[0]));
        float r1 = __fadd_rn(uc[1], select8(acc[1]));
        float r2 = __fadd_rn(uc[2], select8(acc[2]));
        float r3 = __fadd_rn(uc[3], select8(acc[3]));

        float* drow = dst + (size_t)ch * PLANE + (size_t)gy * RS;
        if (gx0 + 3 < P) {
            float4 o; o.x = r0; o.y = r1; o.z = r2; o.w = r3;
            *reinterpret_cast<float4*>(drow + gx0) = o;
        } else {
            if (gx0     < P) drow[gx0]     = r0;
            if (gx0 + 1 < P) drow[gx0 + 1] = r1;
            if (gx0 + 2 < P) drow[gx0 + 2] = r2;
            if (gx0 + 3 < P) drow[gx0 + 3] = r3;
        }
    }
}

// ---------------------------------------------------------------------------
// Crop interiors of 3 f32 planes back into HWC float32 output
// ---------------------------------------------------------------------------
__global__ void crop_kernel(const float* __restrict__ src, float* __restrict__ dst) {
    int idx = blockIdx.x * blockDim.x + threadIdx.x;
    int total = H * W * C;
    if (idx >= total) return;
    int tmp = idx / C;
    int c = idx - tmp * C;
    int y = tmp / W;
    int x = tmp - y * W;
    dst[idx] = src[(size_t)c * PLANE + (size_t)(y + RAD) * RS + (x + RAD)];
}

extern "C" void kernel_launch(void* const* d_in, const int* in_sizes, int n_in,
                              void* d_out, int out_size, void* d_ws, size_t ws_size,
                              hipStream_t stream) {
    const float* img  = (const float*)d_in[0];
    const float* kern = (const float*)d_in[1];
    float* out = (float*)d_out;

    float* b0 = (float*)d_ws;                    // 3 planes
    float* b1 = b0 + (size_t)C * PLANE;          // 3 planes (~102 MB total)

    {
        int total = C * P * P;
        pad_kernel<<<(total + 255) / 256, 256, 0, stream>>>(img, b0);
    }

    dim3 sgrid((P + BX - 1) / BX, (P + BY - 1) / BY, C);
    dim3 sblock(32, 8, 1);
    for (int i = 0; i < NITER; ++i) {
        const float* s = (i & 1) ? b1 : b0;
        float*       d = (i & 1) ? b0 : b1;
        step_kernel<<<sgrid, sblock, 0, stream>>>(s, d, kern);
    }

    {
        int total = H * W * C;
        crop_kernel<<<(total + 255) / 256, 256, 0, stream>>>(b0, out);
    }
}

// Round 9
// 1949.386 us; speedup vs baseline: 1.3553x; 1.3553x over previous
//
#include <hip/hip_runtime.h>

// NUMERIC CONTRACT (proven bit-exact in R8, absmax=0.0): per candidate,
// one __fmaf_rn per support tap, taps in ascending (ky,kx) order, acc
// starts at +0.0f, final u+best via __fadd_rn, argmin strict-< in order
// [LL,LR,RL,RR,Lk,Rk,kL,kR], weights = exact f32 values from d_in[1].
// Any restructuring must preserve each chain's op sequence exactly.

#define H 2048
#define W 2048
#define C 3
#define RAD 5
#define P (H + 2*RAD)           // 2058
#define RS 2064                 // global row stride
#define PLANE ((size_t)P * RS)
#define NITER 10

// Tile: 128 x 16 outputs per block; threads (32,8); each thread: 4 cols x 2 rows
#define BX 128
#define BY 16
#define EX (BX + 2*RAD)         // 138
#define EY (BY + 2*RAD)         // 26
#define LSX 148                 // LDS row stride (float4-aligned, breaks 32-bank period)

__global__ void pad_kernel(const float* __restrict__ img, float* __restrict__ dst) {
    int idx = blockIdx.x * blockDim.x + threadIdx.x;
    int total = C * P * P;
    if (idx >= total) return;
    int c = idx / (P * P);
    int rem = idx - c * (P * P);
    int y = rem / P;
    int x = rem - y * P;
    int ys = min(max(y - RAD, 0), H - 1);
    int xs = min(max(x - RAD, 0), W - 1);
    dst[c * PLANE + (size_t)y * RS + x] = img[((size_t)ys * W + xs) * C + c];
}

__device__ __forceinline__ float select8(const float* a) {
    float best = a[0], ba = fabsf(a[0]), t;
    t = fabsf(a[1]); if (t < ba) { ba = t; best = a[1]; }
    t = fabsf(a[2]); if (t < ba) { ba = t; best = a[2]; }
    t = fabsf(a[3]); if (t < ba) { ba = t; best = a[3]; }
    t = fabsf(a[4]); if (t < ba) { ba = t; best = a[4]; }
    t = fabsf(a[5]); if (t < ba) { ba = t; best = a[5]; }
    t = fabsf(a[6]); if (t < ba) { ba = t; best = a[6]; }
    t = fabsf(a[7]); if (t < ba) { ba = t; best = a[7]; }
    return best;
}

// One row of taps (ky) folded into the 8 chains of 4 pixels.
// Chain order: within this row, each candidate's taps go kx-ascending;
// rows are fed ky-ascending by the caller. Bit-exact per contract.
__device__ __forceinline__ void row_update(float acc[4][8], const float win[16], int ky,
                                           float w36, float c36, float w66, float c66) {
    const bool Lv = (ky <= 5), Rv = (ky >= 5);
    const float wc5 = (ky == 5) ? c36 : w36;   // corner-kernel weight at kx=5
    const float ws5 = (ky == 5) ? c66 : w66;   // side-kernel weight at kx=5
    #pragma unroll
    for (int p = 0; p < 4; ++p) {
        float a;
        if (Lv) {
            a = acc[p][0];                                     // LL: kx 0..5
            a = __fmaf_rn(w36, win[p+0], a); a = __fmaf_rn(w36, win[p+1], a);
            a = __fmaf_rn(w36, win[p+2], a); a = __fmaf_rn(w36, win[p+3], a);
            a = __fmaf_rn(w36, win[p+4], a); a = __fmaf_rn(wc5, win[p+5], a);
            acc[p][0] = a;
            a = acc[p][1];                                     // LR: kx 5..10
            a = __fmaf_rn(wc5, win[p+5], a); a = __fmaf_rn(w36, win[p+6], a);
            a = __fmaf_rn(w36, win[p+7], a); a = __fmaf_rn(w36, win[p+8], a);
            a = __fmaf_rn(w36, win[p+9], a); a = __fmaf_rn(w36, win[p+10], a);
            acc[p][1] = a;
            a = acc[p][4];                                     // Lk: kx 0..10
            a = __fmaf_rn(w66, win[p+0], a); a = __fmaf_rn(w66, win[p+1], a);
            a = __fmaf_rn(w66, win[p+2], a); a = __fmaf_rn(w66, win[p+3], a);
            a = __fmaf_rn(w66, win[p+4], a); a = __fmaf_rn(ws5, win[p+5], a);
            a = __fmaf_rn(w66, win[p+6], a); a = __fmaf_rn(w66, win[p+7], a);
            a = __fmaf_rn(w66, win[p+8], a); a = __fmaf_rn(w66, win[p+9], a);
            a = __fmaf_rn(w66, win[p+10], a);
            acc[p][4] = a;
        }
        if (Rv) {
            a = acc[p][2];                                     // RL: kx 0..5
            a = __fmaf_rn(w36, win[p+0], a); a = __fmaf_rn(w36, win[p+1], a);
            a = __fmaf_rn(w36, win[p+2], a); a = __fmaf_rn(w36, win[p+3], a);
            a = __fmaf_rn(w36, win[p+4], a); a = __fmaf_rn(wc5, win[p+5], a);
            acc[p][2] = a;
            a = acc[p][3];                                     // RR: kx 5..10
            a = __fmaf_rn(wc5, win[p+5], a); a = __fmaf_rn(w36, win[p+6], a);
            a = __fmaf_rn(w36, win[p+7], a); a = __fmaf_rn(w36, win[p+8], a);
            a = __fmaf_rn(w36, win[p+9], a); a = __fmaf_rn(w36, win[p+10], a);
            acc[p][3] = a;
            a = acc[p][5];                                     // Rk: kx 0..10
            a = __fmaf_rn(w66, win[p+0], a); a = __fmaf_rn(w66, win[p+1], a);
            a = __fmaf_rn(w66, win[p+2], a); a = __fmaf_rn(w66, win[p+3], a);
            a = __fmaf_rn(w66, win[p+4], a); a = __fmaf_rn(ws5, win[p+5], a);
            a = __fmaf_rn(w66, win[p+6], a); a = __fmaf_rn(w66, win[p+7], a);
            a = __fmaf_rn(w66, win[p+8], a); a = __fmaf_rn(w66, win[p+9], a);
            a = __fmaf_rn(w66, win[p+10], a);
            acc[p][5] = a;
        }
        a = acc[p][6];                                         // kL: kx 0..5 (all rows)
        a = __fmaf_rn(w66, win[p+0], a); a = __fmaf_rn(w66, win[p+1], a);
        a = __fmaf_rn(w66, win[p+2], a); a = __fmaf_rn(w66, win[p+3], a);
        a = __fmaf_rn(w66, win[p+4], a); a = __fmaf_rn(ws5, win[p+5], a);
        acc[p][6] = a;
        a = acc[p][7];                                         // kR: kx 5..10 (all rows)
        a = __fmaf_rn(ws5, win[p+5], a); a = __fmaf_rn(w66, win[p+6], a);
        a = __fmaf_rn(w66, win[p+7], a); a = __fmaf_rn(w66, win[p+8], a);
        a = __fmaf_rn(w66, win[p+9], a); a = __fmaf_rn(w66, win[p+10], a);
        acc[p][7] = a;
    }
}

__global__ __launch_bounds__(256)
void step_kernel(const float* __restrict__ src, float* __restrict__ dst,
                 const float* __restrict__ kern) {
    __shared__ __align__(16) float sU[EY][LSX];

    const float w36 = kern[0];
    const float c36 = kern[5 * 11 + 5];
    const float w66 = kern[4 * 121];
    const float c66 = kern[4 * 121 + 5 * 11 + 5];

    const int ch = blockIdx.z;
    const float* plane = src + (size_t)ch * PLANE;
    const int x0 = blockIdx.x * BX;
    const int y0 = blockIdx.y * BY;
    const int tx = threadIdx.x, ty = threadIdx.y;
    const int tid = ty * 32 + tx;

    // Stage 26x138 tile (+halo); outside [0,P) is zero (conv zero padding)
    for (int i = tid; i < EY * EX; i += 256) {
        int r   = i / EX;
        int col = i - r * EX;
        int gy = y0 - RAD + r;
        int gx = x0 - RAD + col;
        float v = 0.0f;
        if (gy >= 0 && gy < P && gx >= 0 && gx < P)
            v = plane[(size_t)gy * RS + gx];
        sU[r][col] = v;
    }
    __syncthreads();

    const int rb  = 2 * ty;               // first of 2 output rows (tile coords)
    const int X   = 4 * tx;               // window base col (= first out col - 5)
    const int gy0 = y0 + rb;
    const int gx0 = x0 + X;

    float acc0[4][8], acc1[4][8];
    #pragma unroll
    for (int p = 0; p < 4; ++p)
        #pragma unroll
        for (int i = 0; i < 8; ++i) { acc0[p][i] = 0.0f; acc1[p][i] = 0.0f; }
    float uc0[4], uc1[4];

    // Slide over the 12 staged rows this thread needs; row k serves
    // out-row0 as ky=k (k<=10) and out-row1 as ky=k-1 (k>=1).
    #pragma unroll 1
    for (int k = 0; k < 12; ++k) {
        const float4* prow = reinterpret_cast<const float4*>(&sU[rb + k][X]);
        float4 q0 = prow[0], q1 = prow[1], q2 = prow[2], q3 = prow[3];
        float win[16];
        win[0]=q0.x;  win[1]=q0.y;  win[2]=q0.z;  win[3]=q0.w;
        win[4]=q1.x;  win[5]=q1.y;  win[6]=q1.z;  win[7]=q1.w;
        win[8]=q2.x;  win[9]=q2.y;  win[10]=q2.z; win[11]=q2.w;
        win[12]=q3.x; win[13]=q3.y; win[14]=q3.z; win[15]=q3.w;

        if (k == 5) { uc0[0]=win[5]; uc0[1]=win[6]; uc0[2]=win[7]; uc0[3]=win[8]; }
        if (k == 6) { uc1[0]=win[5]; uc1[1]=win[6]; uc1[2]=win[7]; uc1[3]=win[8]; }

        if (k <= 10) row_update(acc0, win, k,     w36, c36, w66, c66);
        if (k >= 1)  row_update(acc1, win, k - 1, w36, c36, w66, c66);
    }

    float* drow0 = dst + (size_t)ch * PLANE + (size_t)gy0 * RS;
    float* drow1 = drow0 + RS;

    if (gy0 < P) {
        float r0 = __fadd_rn(uc0[0], select8(acc0[0]));
        float r1 = __fadd_rn(uc0[1], select8(acc0[1]));
        float r2 = __fadd_rn(uc0[2], select8(acc0[2]));
        float r3 = __fadd_rn(uc0[3], select8(acc0[3]));
        if (gx0 + 3 < P) {
            float4 o; o.x=r0; o.y=r1; o.z=r2; o.w=r3;
            *reinterpret_cast<float4*>(drow0 + gx0) = o;
        } else {
            if (gx0     < P) drow0[gx0]     = r0;
            if (gx0 + 1 < P) drow0[gx0 + 1] = r1;
            if (gx0 + 2 < P) drow0[gx0 + 2] = r2;
            if (gx0 + 3 < P) drow0[gx0 + 3] = r3;
        }
    }
    if (gy0 + 1 < P) {
        float r0 = __fadd_rn(uc1[0], select8(acc1[0]));
        float r1 = __fadd_rn(uc1[1], select8(acc1[1]));
        float r2 = __fadd_rn(uc1[2], select8(acc1[2]));
        float r3 = __fadd_rn(uc1[3], select8(acc1[3]));
        if (gx0 + 3 < P) {
            float4 o; o.x=r0; o.y=r1; o.z=r2; o.w=r3;
            *reinterpret_cast<float4*>(drow1 + gx0) = o;
        } else {
            if (gx0     < P) drow1[gx0]     = r0;
            if (gx0 + 1 < P) drow1[gx0 + 1] = r1;
            if (gx0 + 2 < P) drow1[gx0 + 2] = r2;
            if (gx0 + 3 < P) drow1[gx0 + 3] = r3;
        }
    }
}

__global__ void crop_kernel(const float* __restrict__ src, float* __restrict__ dst) {
    int idx = blockIdx.x * blockDim.x + threadIdx.x;
    int total = H * W * C;
    if (idx >= total) return;
    int tmp = idx / C;
    int c = idx - tmp * C;
    int y = tmp / W;
    int x = tmp - y * W;
    dst[idx] = src[(size_t)c * PLANE + (size_t)(y + RAD) * RS + (x + RAD)];
}

extern "C" void kernel_launch(void* const* d_in, const int* in_sizes, int n_in,
                              void* d_out, int out_size, void* d_ws, size_t ws_size,
                              hipStream_t stream) {
    const float* img  = (const float*)d_in[0];
    const float* kern = (const float*)d_in[1];
    float* out = (float*)d_out;

    float* b0 = (float*)d_ws;                    // 3 planes
    float* b1 = b0 + (size_t)C * PLANE;          // 3 planes (~102 MB total)

    {
        int total = C * P * P;
        pad_kernel<<<(total + 255) / 256, 256, 0, stream>>>(img, b0);
    }

    dim3 sgrid((P + BX - 1) / BX, (P + BY - 1) / BY, C);
    dim3 sblock(32, 8, 1);
    for (int i = 0; i < NITER; ++i) {
        const float* s = (i & 1) ? b1 : b0;
        float*       d = (i & 1) ? b0 : b1;
        step_kernel<<<sgrid, sblock, 0, stream>>>(s, d, kern);
    }

    {
        int total = H * W * C;
        crop_kernel<<<(total + 255) / 256, 256, 0, stream>>>(b0, out);
    }
}